// Round 1
// baseline (30042.905 us; speedup 1.0000x reference)
//
#include <hip/hip_runtime.h>

#define BB 512
#define LL 2000
#define DD 16
#define HH 128
#define WD 256
#define NLBL 10
#define NSTEPS 500
#define G 16
#define NWG (BB / G)
#define NTHR 512

typedef __bf16 bf16x8 __attribute__((ext_vector_type(8)));
typedef float f32x4 __attribute__((ext_vector_type(4)));

__device__ __forceinline__ unsigned short f2bf(float f) {
  unsigned int u = __float_as_uint(f);
  u += 0x7FFFu + ((u >> 16) & 1u);
  return (unsigned short)(u >> 16);
}

// XOR-swizzled element offset into a [G][WD] bf16 LDS tile (8-elem chunks)
__device__ __forceinline__ int swz(int r, int c) {
  return r * WD + ((((c >> 3) ^ (r & 7)) << 3) | (c & 7));
}

__device__ __forceinline__ bf16x8 ldfrag(const unsigned short* buf, int row, int chunk) {
  return *reinterpret_cast<const bf16x8*>(buf + row * WD + ((chunk ^ (row & 7)) << 3));
}

struct __align__(16) SM {
  float Y[G][HH];
  float K1[G][HH];
  float F[G][HH];
  unsigned short X[G * WD];   // swizzled bf16 activations (input / H2)
  unsigned short Hb[G * WD];  // swizzled bf16 H1
  float dx[2][G][DD];
  float b1[WD], b2[WD];
  float b3[HH * DD];
  float tau_tab[2 * NSTEPS];
  unsigned short idx_tab[2 * NSTEPS];
  float logits[G * NLBL];
};

__global__ void prep(const float* __restrict__ W1, const float* __restrict__ W2,
                     const float* __restrict__ W3,
                     unsigned short* __restrict__ w1b, unsigned short* __restrict__ w2b,
                     unsigned short* __restrict__ w3b) {
  int i = blockIdx.x * blockDim.x + threadIdx.x;
  if (i < HH * DD * WD) w3b[i] = f2bf(W3[i]);
  if (i < WD * WD) w2b[i] = f2bf(W2[i]);
  if (i < WD * HH) w1b[i] = f2bf(W1[i]);
}

__global__ __launch_bounds__(NTHR, 2) void cde_main(
    const float* __restrict__ ts, const float* __restrict__ coeffs,
    const float* __restrict__ x0,
    const float* __restrict__ b1g, const float* __restrict__ b2g, const float* __restrict__ b3g,
    const float* __restrict__ Wl1, const float* __restrict__ bl1,
    const float* __restrict__ Wl2, const float* __restrict__ bl2,
    const unsigned short* __restrict__ w1b, const unsigned short* __restrict__ w2b,
    const unsigned short* __restrict__ w3b,
    float* __restrict__ out) {
  __shared__ SM sm;
  const int tid = threadIdx.x;
  const int gb = blockIdx.x * G;
  const int w = tid >> 6, lane = tid & 63;
  const int row16 = lane & 15, kg = lane >> 4;

  const float ts0 = ts[0];
  const float dt = (ts[LL - 1] - ts0) / (float)NSTEPS;

  for (int i = tid; i < WD; i += NTHR) { sm.b1[i] = b1g[i]; sm.b2[i] = b2g[i]; }
  for (int i = tid; i < HH * DD; i += NTHR) sm.b3[i] = b3g[i];

  // idx/tau table, bit-faithful to reference time arithmetic
  for (int e = tid; e < 2 * NSTEPS; e += NTHR) {
    int kk = e >> 1;
    float t = ts0 + (float)kk * dt;
    if (e & 1) t = t + dt;
    int lo = 0, hi = LL;
    while (lo < hi) { int m = (lo + hi) >> 1; if (ts[m] <= t) lo = m + 1; else hi = m; }
    int idx = lo - 1;
    if (idx < 0) idx = 0;
    if (idx > LL - 2) idx = LL - 2;
    sm.idx_tab[e] = (unsigned short)idx;
    sm.tau_tab[e] = t - ts[idx];
  }

  // y0 = x0 @ Wl1^T + bl1
  for (int i = tid; i < G * HH; i += NTHR) {
    int r = i >> 7, h = i & (HH - 1);
    float s = bl1[h];
    const float* xr = x0 + (size_t)(gb + r) * DD;
    const float* wr = Wl1 + (size_t)h * DD;
#pragma unroll
    for (int d = 0; d < DD; ++d) s += xr[d] * wr[d];
    sm.Y[r][h] = s;
  }

  // persistent W1/W2 B-fragments (B[k][n] = W[n][k]; lane: n=row16, k=kg*8+e)
  bf16x8 w1f[2][4], w2f[2][8];
  const uint4* w1p = reinterpret_cast<const uint4*>(w1b);
  const uint4* w2p = reinterpret_cast<const uint4*>(w2b);
  const uint4* w3p = reinterpret_cast<const uint4*>(w3b);
#pragma unroll
  for (int tt = 0; tt < 2; ++tt) {
    int n = (w + tt * 8) * 16 + row16;
#pragma unroll
    for (int s = 0; s < 4; ++s) w1f[tt][s] = __builtin_bit_cast(bf16x8, w1p[n * 16 + s * 4 + kg]);
#pragma unroll
    for (int s = 0; s < 8; ++s) w2f[tt][s] = __builtin_bit_cast(bf16x8, w2p[n * 32 + s * 4 + kg]);
  }
  __syncthreads();

  for (int k = 0; k < NSTEPS; ++k) {
    for (int mode = 0; mode < 2; ++mode) {
      float(*dest)[HH] = mode ? sm.F : sm.K1;

      // ---- phase A: stage input activations (bf16, swizzled) + dX prefetch
      for (int i = tid; i < G * HH; i += NTHR) {
        int r = i >> 7, c = i & (HH - 1);
        float v = sm.Y[r][c];
        if (mode) v += dt * sm.K1[r][c];
        sm.X[swz(r, c)] = f2bf(v);
      }
      if (mode == 0) {  // compute dX for BOTH Heun stages now
        int which = tid >> 8, j = tid & 255;
        int r = j >> 4, d = j & 15;
        int e = 2 * k + which;
        int idx = sm.idx_tab[e];
        float tau = sm.tau_tab[e];
        const float* cb = coeffs + ((size_t)(gb + r) * 4 * (LL - 1) + idx) * DD + d;
        float c0 = cb[0];                        // d_
        float c1 = cb[(size_t)(LL - 1) * DD];    // c_
        float c2 = cb[(size_t)2 * (LL - 1) * DD];// b_
        sm.dx[which][r][d] = c2 + 2.0f * tau * c1 + 3.0f * tau * tau * c0;
      }
      __syncthreads();

      // ---- phase B: H1 = relu(X @ W1^T + b1)   (M=16,N=256,K=128)
      {
        bf16x8 a[4];
#pragma unroll
        for (int s = 0; s < 4; ++s) a[s] = ldfrag(sm.X, row16, s * 4 + kg);
#pragma unroll
        for (int tt = 0; tt < 2; ++tt) {
          f32x4 acc = {0.f, 0.f, 0.f, 0.f};
#pragma unroll
          for (int s = 0; s < 4; ++s)
            acc = __builtin_amdgcn_mfma_f32_16x16x32_bf16(a[s], w1f[tt][s], acc, 0, 0, 0);
          int n = (w + tt * 8) * 16 + row16;
#pragma unroll
          for (int v = 0; v < 4; ++v) {
            int r = kg * 4 + v;
            float o = acc[v] + sm.b1[n];
            sm.Hb[swz(r, n)] = f2bf(fmaxf(o, 0.f));
          }
        }
      }
      __syncthreads();

      // ---- phase C: H2 = relu(H1 @ W2^T + b2)  (M=16,N=256,K=256) -> X
      {
        bf16x8 a[8];
#pragma unroll
        for (int s = 0; s < 8; ++s) a[s] = ldfrag(sm.Hb, row16, s * 4 + kg);
#pragma unroll
        for (int tt = 0; tt < 2; ++tt) {
          f32x4 acc = {0.f, 0.f, 0.f, 0.f};
#pragma unroll
          for (int s = 0; s < 8; ++s)
            acc = __builtin_amdgcn_mfma_f32_16x16x32_bf16(a[s], w2f[tt][s], acc, 0, 0, 0);
          int n = (w + tt * 8) * 16 + row16;
#pragma unroll
          for (int v = 0; v < 4; ++v) {
            int r = kg * 4 + v;
            float o = acc[v] + sm.b2[n];
            sm.X[swz(r, n)] = f2bf(fmaxf(o, 0.f));
          }
        }
      }
      __syncthreads();

      // ---- phase D: O = tanh(H2 @ W3^T + b3); F = sum_d O*dX
      {
        bf16x8 a[8];
#pragma unroll
        for (int s = 0; s < 8; ++s) a[s] = ldfrag(sm.X, row16, s * 4 + kg);
        for (int j = 0; j < 16; ++j) {
          int nt = w + j * 8;             // h index
          int nrow = nt * 16 + row16;     // W3 row (= h*16 + d), d == row16
          bf16x8 bfr[8];
#pragma unroll
          for (int s = 0; s < 8; ++s)
            bfr[s] = __builtin_bit_cast(bf16x8, w3p[nrow * 32 + s * 4 + kg]);
          f32x4 acc = {0.f, 0.f, 0.f, 0.f};
#pragma unroll
          for (int s = 0; s < 8; ++s)
            acc = __builtin_amdgcn_mfma_f32_16x16x32_bf16(a[s], bfr[s], acc, 0, 0, 0);
          float p[4];
#pragma unroll
          for (int v = 0; v < 4; ++v) {
            int r = kg * 4 + v;
            float o = acc[v] + sm.b3[nrow];
            float e2 = __expf(2.0f * o);
            float T = 1.0f - 2.0f / (e2 + 1.0f);
            p[v] = T * sm.dx[mode][r][row16];
          }
#pragma unroll
          for (int m = 1; m < 16; m <<= 1) {
#pragma unroll
            for (int v = 0; v < 4; ++v) p[v] += __shfl_xor(p[v], m);
          }
          if (row16 == 0) {
#pragma unroll
            for (int v = 0; v < 4; ++v) dest[kg * 4 + v][nt] = p[v];
          }
        }
      }
      __syncthreads();
    }

    // ---- Heun update
    for (int i = tid; i < G * HH; i += NTHR) {
      int r = i >> 7, c = i & (HH - 1);
      sm.Y[r][c] += 0.5f * dt * (sm.K1[r][c] + sm.F[r][c]);
    }
    __syncthreads();
  }

  // ---- classifier + softmax
  if (tid < G * NLBL) {
    int r = tid / NLBL, c = tid % NLBL;
    float s = bl2[c];
    const float* wr = Wl2 + (size_t)c * HH;
#pragma unroll 4
    for (int h = 0; h < HH; ++h) s += sm.Y[r][h] * wr[h];
    sm.logits[tid] = s;
  }
  __syncthreads();
  if (tid < G) {
    float mx = -1e30f;
#pragma unroll
    for (int c = 0; c < NLBL; ++c) mx = fmaxf(mx, sm.logits[tid * NLBL + c]);
    float e[NLBL], sum = 0.f;
#pragma unroll
    for (int c = 0; c < NLBL; ++c) { e[c] = expf(sm.logits[tid * NLBL + c] - mx); sum += e[c]; }
    float inv = 1.0f / sum;
#pragma unroll
    for (int c = 0; c < NLBL; ++c) out[(size_t)(gb + tid) * NLBL + c] = e[c] * inv;
  }
}

extern "C" void kernel_launch(void* const* d_in, const int* in_sizes, int n_in,
                              void* d_out, int out_size, void* d_ws, size_t ws_size,
                              hipStream_t stream) {
  (void)in_sizes; (void)n_in; (void)out_size; (void)ws_size;
  const float* ts = (const float*)d_in[0];
  const float* coeffs = (const float*)d_in[1];
  const float* x0 = (const float*)d_in[2];
  const float* W1 = (const float*)d_in[3];
  const float* b1 = (const float*)d_in[4];
  const float* W2 = (const float*)d_in[5];
  const float* b2 = (const float*)d_in[6];
  const float* W3 = (const float*)d_in[7];
  const float* b3 = (const float*)d_in[8];
  const float* Wl1 = (const float*)d_in[9];
  const float* bl1 = (const float*)d_in[10];
  const float* Wl2 = (const float*)d_in[11];
  const float* bl2 = (const float*)d_in[12];

  unsigned short* w3b = (unsigned short*)d_ws;                 // 524288 bf16
  unsigned short* w2b = w3b + (HH * DD * WD);                  // 65536 bf16
  unsigned short* w1b = w2b + (WD * WD);                       // 32768 bf16

  prep<<<2048, 256, 0, stream>>>(W1, W2, W3, w1b, w2b, w3b);
  cde_main<<<NWG, NTHR, 0, stream>>>(ts, coeffs, x0, b1, b2, b3, Wl1, bl1, Wl2, bl2,
                                     w1b, w2b, w3b, (float*)d_out);
}